// Round 13
// baseline (168.360 us; speedup 1.0000x reference)
//
#include <hip/hip_runtime.h>
#include <hip/hip_bf16.h>

// Problem constants (match reference)
#define BB      4
#define SS      4096
#define WW      41
#define SDRN    2048
#define HID     2048
#define NTOK    (BB * SS)
#define EPS_LN  1e-5f
#define NSLICE  4
#define SLICE_H 512        // HID / NSLICE
#define PADID   SDRN       // index of the all-zeros padding row
#define TROWS   (SDRN + 1) // table rows incl. zero row
#define UIDS    48         // padded id-list stride (ints)

typedef float        f32x4 __attribute__((ext_vector_type(4)));
typedef float        f32x2 __attribute__((ext_vector_type(2)));
typedef unsigned int u32x4 __attribute__((ext_vector_type(4)));

static __device__ __forceinline__ unsigned short bf16bits(float f) {
    return __builtin_bit_cast(unsigned short, __float2bfloat16(f));
}

// ---------------------------------------------------------------------------
// Kernel 1a: transpose+convert proj_w [HID][SDRN] f32 -> Wt [TROWS][HID] bf16
// ---------------------------------------------------------------------------
__global__ __launch_bounds__(256) void transpose_cvt(const float* __restrict__ in,
                                                     __hip_bfloat16* __restrict__ out) {
    __shared__ float tile[32][33];
    int x = blockIdx.x * 32 + threadIdx.x;  // n
    int y = blockIdx.y * 32 + threadIdx.y;  // h
#pragma unroll
    for (int j = 0; j < 32; j += 8)
        tile[threadIdx.y + j][threadIdx.x] = in[(size_t)(y + j) * SDRN + x];
    __syncthreads();
    x = blockIdx.y * 32 + threadIdx.x;      // h
    y = blockIdx.x * 32 + threadIdx.y;      // n
#pragma unroll
    for (int j = 0; j < 32; j += 8)
        out[(size_t)(y + j) * HID + x] = __float2bfloat16(tile[threadIdx.x][threadIdx.y + j]);
}

// Kernel 1b: zero the padding row (row PADID = 4096 B)
__global__ void zero_pad_row(__hip_bfloat16* __restrict__ Wt) {
    u32x4 z = {0u, 0u, 0u, 0u};
    *((u32x4*)(Wt + (size_t)PADID * HID) + threadIdx.x) = z;  // 256 x 16 B
}

// ---------------------------------------------------------------------------
// Kernel 1c: per-token dedupe (hoisted, R12-proven). One wave per token.
// ---------------------------------------------------------------------------
__global__ __launch_bounds__(256) void dedup_k(const int* __restrict__ ids,
                                               int* __restrict__ uidp,
                                               int* __restrict__ ucnt) {
    const int wave  = threadIdx.x >> 6;
    const int lane  = threadIdx.x & 63;
    const int token = blockIdx.x * 4 + wave;

    int myid = (lane < WW) ? ids[(size_t)token * WW + lane] : 0;
    int keep = (lane < WW) ? 1 : 0;
#pragma unroll
    for (int j = 0; j < WW; ++j) {
        const int idj = __shfl(myid, j);
        if (j < lane && lane < WW && idj == myid) keep = 0;
    }
    const unsigned long long km = __ballot(keep);
    const int nkeep = __popcll(km);
    const int nk4   = (nkeep + 3) & ~3;             // <= 44
    int* dst = uidp + (size_t)token * UIDS;
    if (keep) {
        const int rank = __popcll(km & ((1ull << lane) - 1ull));
        dst[rank] = myid;
    }
    if (lane >= nkeep && lane < 44) dst[lane] = PADID;
    if (lane == 0) ucnt[token] = nk4;
}

#define ACC8(u, a0, a1, a2, a3)                                                 \
    { f32x2 t;                                                                  \
      t.x = __uint_as_float((u).x << 16); t.y = __uint_as_float((u).x & 0xffff0000u); a0 += t; \
      t.x = __uint_as_float((u).y << 16); t.y = __uint_as_float((u).y & 0xffff0000u); a1 += t; \
      t.x = __uint_as_float((u).z << 16); t.y = __uint_as_float((u).z & 0xffff0000u); a2 += t; \
      t.x = __uint_as_float((u).w << 16); t.y = __uint_as_float((u).w & 0xffff0000u); a3 += t; }

// ---------------------------------------------------------------------------
// Pass 1 (2 tokens per wave): each wave gathers one 512-wide h-slice for TWO
// tokens over the same L2-resident table slice -> 8 loads in flight, two
// independent unpack chains. Arithmetic per token identical to R12 (exact);
// shorter id list just processes extra PADID zero-rows.
// ---------------------------------------------------------------------------
__global__ __launch_bounds__(256) void sdr_gather_p1_two(
    const int* __restrict__ uidp, const int* __restrict__ ucnt,
    const __hip_bfloat16* __restrict__ Wt,
    __hip_bfloat16* __restrict__ xbf, float2* __restrict__ partials) {
    const int b     = blockIdx.x;                   // [0, NTOK/2)
    const int sub   = b & 1;
    const int slice = (b & 7) >> 1;                 // 4 slices x 2 XCDs
    const int tg    = ((b >> 3) << 1) | sub;        // [0, 2048)
    const int wave  = threadIdx.x >> 6;
    const int lane  = threadIdx.x & 63;
    const int pb    = tg * 4 + wave;                // token-pair index [0, 8192)
    const int tA    = pb * 2;
    const int tB    = tA + 1;

    const int cidA = uidp[(size_t)tA * UIDS + (lane < 44 ? lane : 0)];
    const int cidB = uidp[(size_t)tB * UIDS + (lane < 44 ? lane : 0)];
    const int nkA  = __builtin_amdgcn_readfirstlane(ucnt[tA]);
    const int nkB  = __builtin_amdgcn_readfirstlane(ucnt[tB]);
    const int nk   = nkA > nkB ? nkA : nkB;         // both lists PADID-padded to 44

    f32x2 aA0 = {0.f, 0.f}, aA1 = {0.f, 0.f}, aA2 = {0.f, 0.f}, aA3 = {0.f, 0.f};
    f32x2 aB0 = {0.f, 0.f}, aB1 = {0.f, 0.f}, aB2 = {0.f, 0.f}, aB3 = {0.f, 0.f};
    const int lofs = slice * SLICE_H + lane * 8;    // element offset in a row
    const unsigned int* W32 = (const unsigned int*)Wt;
    const int lo2 = lofs >> 1;

    for (int i = 0; i < nk; i += 4) {
        const int a0i = __builtin_amdgcn_readlane(cidA, i);
        const int a1i = __builtin_amdgcn_readlane(cidA, i + 1);
        const int a2i = __builtin_amdgcn_readlane(cidA, i + 2);
        const int a3i = __builtin_amdgcn_readlane(cidA, i + 3);
        const int b0i = __builtin_amdgcn_readlane(cidB, i);
        const int b1i = __builtin_amdgcn_readlane(cidB, i + 1);
        const int b2i = __builtin_amdgcn_readlane(cidB, i + 2);
        const int b3i = __builtin_amdgcn_readlane(cidB, i + 3);
        const u32x4 uA0 = *(const u32x4*)(W32 + (size_t)a0i * (HID / 2) + lo2);
        const u32x4 uA1 = *(const u32x4*)(W32 + (size_t)a1i * (HID / 2) + lo2);
        const u32x4 uA2 = *(const u32x4*)(W32 + (size_t)a2i * (HID / 2) + lo2);
        const u32x4 uA3 = *(const u32x4*)(W32 + (size_t)a3i * (HID / 2) + lo2);
        const u32x4 uB0 = *(const u32x4*)(W32 + (size_t)b0i * (HID / 2) + lo2);
        const u32x4 uB1 = *(const u32x4*)(W32 + (size_t)b1i * (HID / 2) + lo2);
        const u32x4 uB2 = *(const u32x4*)(W32 + (size_t)b2i * (HID / 2) + lo2);
        const u32x4 uB3 = *(const u32x4*)(W32 + (size_t)b3i * (HID / 2) + lo2);
        ACC8(uA0, aA0, aA1, aA2, aA3);
        ACC8(uB0, aB0, aB1, aB2, aB3);
        ACC8(uA1, aA0, aA1, aA2, aA3);
        ACC8(uB1, aB0, aB1, aB2, aB3);
        ACC8(uA2, aA0, aA1, aA2, aA3);
        ACC8(uB2, aB0, aB1, aB2, aB3);
        ACC8(uA3, aA0, aA1, aA2, aA3);
        ACC8(uB3, aB0, aB1, aB2, aB3);
    }

    // per-wave partials (sum, sumsq) for both tokens
    float sA  = aA0.x + aA0.y + aA1.x + aA1.y + aA2.x + aA2.y + aA3.x + aA3.y;
    float sA2 = aA0.x * aA0.x + aA0.y * aA0.y + aA1.x * aA1.x + aA1.y * aA1.y +
                aA2.x * aA2.x + aA2.y * aA2.y + aA3.x * aA3.x + aA3.y * aA3.y;
    float sB  = aB0.x + aB0.y + aB1.x + aB1.y + aB2.x + aB2.y + aB3.x + aB3.y;
    float sB2 = aB0.x * aB0.x + aB0.y * aB0.y + aB1.x * aB1.x + aB1.y * aB1.y +
                aB2.x * aB2.x + aB2.y * aB2.y + aB3.x * aB3.x + aB3.y * aB3.y;
#pragma unroll
    for (int off = 1; off < 64; off <<= 1) {
        sA  += __shfl_xor(sA, off);
        sA2 += __shfl_xor(sA2, off);
        sB  += __shfl_xor(sB, off);
        sB2 += __shfl_xor(sB2, off);
    }
    if (lane == 0) {
        float2 pA; pA.x = sA; pA.y = sA2;
        float2 pB; pB.x = sB; pB.y = sB2;
        partials[(size_t)tA * NSLICE + slice] = pA;
        partials[(size_t)tB * NSLICE + slice] = pB;
    }

    // write pre-LN x (bf16, nontemporal)
    u32x4 oA, oB;
    oA.x = (unsigned)bf16bits(aA0.x) | ((unsigned)bf16bits(aA0.y) << 16);
    oA.y = (unsigned)bf16bits(aA1.x) | ((unsigned)bf16bits(aA1.y) << 16);
    oA.z = (unsigned)bf16bits(aA2.x) | ((unsigned)bf16bits(aA2.y) << 16);
    oA.w = (unsigned)bf16bits(aA3.x) | ((unsigned)bf16bits(aA3.y) << 16);
    oB.x = (unsigned)bf16bits(aB0.x) | ((unsigned)bf16bits(aB0.y) << 16);
    oB.y = (unsigned)bf16bits(aB1.x) | ((unsigned)bf16bits(aB1.y) << 16);
    oB.z = (unsigned)bf16bits(aB2.x) | ((unsigned)bf16bits(aB2.y) << 16);
    oB.w = (unsigned)bf16bits(aB3.x) | ((unsigned)bf16bits(aB3.y) << 16);
    __builtin_nontemporal_store(oA, (u32x4*)(xbf + (size_t)tA * HID + lofs));
    __builtin_nontemporal_store(oB, (u32x4*)(xbf + (size_t)tB * HID + lofs));
}

// ---------------------------------------------------------------------------
// Pass 1 fallback (R10-proven single-token, inline dedupe), XBF variants.
// ---------------------------------------------------------------------------
template <bool XBF>
__global__ __launch_bounds__(256) void sdr_gather_p1(
    const int* __restrict__ ids, const __hip_bfloat16* __restrict__ Wt,
    void* __restrict__ xout, float2* __restrict__ partials) {
    const int b     = blockIdx.x;
    const int sub   = b & 1;
    const int slice = (b & 7) >> 1;
    const int tg    = ((b >> 3) << 1) | sub;
    const int wave  = threadIdx.x >> 6;
    const int lane  = threadIdx.x & 63;
    const int token = tg * 4 + wave;

    __shared__ int s_uids[4][44];

    int myid = (lane < WW) ? ids[(size_t)token * WW + lane] : 0;
    int keep = (lane < WW) ? 1 : 0;
#pragma unroll
    for (int j = 0; j < WW; ++j) {
        const int idj = __shfl(myid, j);
        if (j < lane && lane < WW && idj == myid) keep = 0;
    }
    const unsigned long long km = __ballot(keep);
    const int nkeep = __popcll(km);
    const int nk4   = (nkeep + 3) & ~3;
    if (keep) {
        const int rank = __popcll(km & ((1ull << lane) - 1ull));
        s_uids[wave][rank] = myid;
    }
    if (lane >= nkeep && lane < nk4) s_uids[wave][lane] = PADID;
    const int cid = s_uids[wave][lane < 44 ? lane : 0];

    f32x2 a0 = {0.f, 0.f}, a1 = {0.f, 0.f}, a2 = {0.f, 0.f}, a3 = {0.f, 0.f};
    const int lofs = slice * SLICE_H + lane * 8;

    for (int i = 0; i < nk4; i += 4) {
        const int id0 = __builtin_amdgcn_readlane(cid, i);
        const int id1 = __builtin_amdgcn_readlane(cid, i + 1);
        const int id2 = __builtin_amdgcn_readlane(cid, i + 2);
        const int id3 = __builtin_amdgcn_readlane(cid, i + 3);
        const u32x4 u0 = *(const u32x4*)((const unsigned int*)Wt + (size_t)id0 * (HID / 2) + (lofs >> 1));
        const u32x4 u1 = *(const u32x4*)((const unsigned int*)Wt + (size_t)id1 * (HID / 2) + (lofs >> 1));
        const u32x4 u2 = *(const u32x4*)((const unsigned int*)Wt + (size_t)id2 * (HID / 2) + (lofs >> 1));
        const u32x4 u3 = *(const u32x4*)((const unsigned int*)Wt + (size_t)id3 * (HID / 2) + (lofs >> 1));
        ACC8(u0, a0, a1, a2, a3);
        ACC8(u1, a0, a1, a2, a3);
        ACC8(u2, a0, a1, a2, a3);
        ACC8(u3, a0, a1, a2, a3);
    }

    float s  = a0.x + a0.y + a1.x + a1.y + a2.x + a2.y + a3.x + a3.y;
    float s2 = a0.x * a0.x + a0.y * a0.y + a1.x * a1.x + a1.y * a1.y +
               a2.x * a2.x + a2.y * a2.y + a3.x * a3.x + a3.y * a3.y;
#pragma unroll
    for (int off = 1; off < 64; off <<= 1) {
        s  += __shfl_xor(s, off);
        s2 += __shfl_xor(s2, off);
    }
    if (lane == 0) {
        float2 p; p.x = s; p.y = s2;
        partials[(size_t)token * NSLICE + slice] = p;
    }

    if (XBF) {
        u32x4 o;
        o.x = (unsigned)bf16bits(a0.x) | ((unsigned)bf16bits(a0.y) << 16);
        o.y = (unsigned)bf16bits(a1.x) | ((unsigned)bf16bits(a1.y) << 16);
        o.z = (unsigned)bf16bits(a2.x) | ((unsigned)bf16bits(a2.y) << 16);
        o.w = (unsigned)bf16bits(a3.x) | ((unsigned)bf16bits(a3.y) << 16);
        __hip_bfloat16* xb = (__hip_bfloat16*)xout;
        __builtin_nontemporal_store(o, (u32x4*)(xb + (size_t)token * HID + lofs));
    } else {
        float* xf = (float*)xout;
        f32x4 v0; v0.x = a0.x; v0.y = a0.y; v0.z = a1.x; v0.w = a1.y;
        f32x4 v1; v1.x = a2.x; v1.y = a2.y; v1.z = a3.x; v1.w = a3.y;
        f32x4* xr = (f32x4*)(xf + (size_t)token * HID + lofs);
        __builtin_nontemporal_store(v0, xr);
        __builtin_nontemporal_store(v1, xr + 1);
    }
}

// ---------------------------------------------------------------------------
// Pass 2a: x is bf16 in ws -> normalize -> f32 out
// ---------------------------------------------------------------------------
__global__ __launch_bounds__(256) void sdr_ln_p2_bf(
    const __hip_bfloat16* __restrict__ xbf, const float2* __restrict__ partials,
    const float* __restrict__ gamma, const float* __restrict__ beta,
    float* __restrict__ out) {
    const int token = blockIdx.x;
    const int tid   = threadIdx.x;

    float s = 0.f, s2 = 0.f;
#pragma unroll
    for (int j = 0; j < NSLICE; ++j) {
        const float2 p = partials[(size_t)token * NSLICE + j];
        s += p.x; s2 += p.y;
    }
    const float mean = s * (1.0f / HID);
    const float var  = s2 * (1.0f / HID) - mean * mean;
    const float rstd = rsqrtf(var + EPS_LN);

    const u32x4 u = *((const u32x4*)(xbf + (size_t)token * HID) + tid);
    float xv[8];
    xv[0] = __uint_as_float(u.x << 16); xv[1] = __uint_as_float(u.x & 0xffff0000u);
    xv[2] = __uint_as_float(u.y << 16); xv[3] = __uint_as_float(u.y & 0xffff0000u);
    xv[4] = __uint_as_float(u.z << 16); xv[5] = __uint_as_float(u.z & 0xffff0000u);
    xv[6] = __uint_as_float(u.w << 16); xv[7] = __uint_as_float(u.w & 0xffff0000u);

    const f32x4* g4 = (const f32x4*)gamma + tid * 2;
    const f32x4* b4 = (const f32x4*)beta  + tid * 2;
    const f32x4 g0 = g4[0], g1 = g4[1];
    const f32x4 be0 = b4[0], be1 = b4[1];
    f32x4 r0, r1;
    r0.x = (xv[0] - mean) * rstd * g0.x + be0.x;
    r0.y = (xv[1] - mean) * rstd * g0.y + be0.y;
    r0.z = (xv[2] - mean) * rstd * g0.z + be0.z;
    r0.w = (xv[3] - mean) * rstd * g0.w + be0.w;
    r1.x = (xv[4] - mean) * rstd * g1.x + be1.x;
    r1.y = (xv[5] - mean) * rstd * g1.y + be1.y;
    r1.z = (xv[6] - mean) * rstd * g1.z + be1.z;
    r1.w = (xv[7] - mean) * rstd * g1.w + be1.w;
    f32x4* o4 = (f32x4*)(out + (size_t)token * HID) + tid * 2;
    __builtin_nontemporal_store(r0, o4);
    __builtin_nontemporal_store(r1, o4 + 1);
}

// ---------------------------------------------------------------------------
// Pass 2b: x is f32 in d_out -> normalize in place
// ---------------------------------------------------------------------------
__global__ __launch_bounds__(256) void sdr_ln_p2_inplace(
    float* __restrict__ x, const float2* __restrict__ partials,
    const float* __restrict__ gamma, const float* __restrict__ beta) {
    const int token = blockIdx.x;
    const int tid   = threadIdx.x;

    float s = 0.f, s2 = 0.f;
#pragma unroll
    for (int j = 0; j < NSLICE; ++j) {
        const float2 p = partials[(size_t)token * NSLICE + j];
        s += p.x; s2 += p.y;
    }
    const float mean = s * (1.0f / HID);
    const float var  = s2 * (1.0f / HID) - mean * mean;
    const float rstd = rsqrtf(var + EPS_LN);

    float4*       xr = (float4*)(x + (size_t)token * HID) + tid * 2;
    const float4* g4 = (const float4*)gamma + tid * 2;
    const float4* b4 = (const float4*)beta  + tid * 2;
    float4 a = xr[0], bq = xr[1];
    const float4 g0 = g4[0], g1 = g4[1];
    const float4 be0 = b4[0], be1 = b4[1];
    a.x  = (a.x  - mean) * rstd * g0.x + be0.x;
    a.y  = (a.y  - mean) * rstd * g0.y + be0.y;
    a.z  = (a.z  - mean) * rstd * g0.z + be0.z;
    a.w  = (a.w  - mean) * rstd * g0.w + be0.w;
    bq.x = (bq.x - mean) * rstd * g1.x + be1.x;
    bq.y = (bq.y - mean) * rstd * g1.y + be1.y;
    bq.z = (bq.z - mean) * rstd * g1.z + be1.z;
    bq.w = (bq.w - mean) * rstd * g1.w + be1.w;
    xr[0] = a;
    xr[1] = bq;
}

// ---------------------------------------------------------------------------
// Fallback (tiny ws): gather directly from proj_w columns, fused LN.
// ---------------------------------------------------------------------------
__global__ __launch_bounds__(256) void sdr_gather_ln_notr(
    const int* __restrict__ ids, const float* __restrict__ W,
    const float* __restrict__ gamma, const float* __restrict__ beta,
    float* __restrict__ out) {
    const int token = blockIdx.x;
    const int tid   = threadIdx.x;

    __shared__ int   s_ids[WW];
    __shared__ int   s_keep[WW];
    __shared__ float s_red[8];

    if (tid < WW) s_ids[tid] = ids[(size_t)token * WW + tid];
    __syncthreads();
    if (tid < WW) {
        const int v = s_ids[tid];
        int keep = 1;
        for (int j = 0; j < tid; ++j)
            if (s_ids[j] == v) { keep = 0; break; }
        s_keep[tid] = keep;
    }
    __syncthreads();

    float acc[8] = {0.f};
    for (int i = 0; i < WW; ++i) {
        if (!s_keep[i]) continue;
        const int id = s_ids[i];
#pragma unroll
        for (int j = 0; j < 8; ++j) {
            const int h = tid * 8 + j;
            acc[j] += W[(size_t)h * SDRN + id];
        }
    }
    float s = 0.f, s2 = 0.f;
#pragma unroll
    for (int j = 0; j < 8; ++j) { s += acc[j]; s2 += acc[j] * acc[j]; }
#pragma unroll
    for (int off = 1; off < 64; off <<= 1) {
        s  += __shfl_xor(s, off);
        s2 += __shfl_xor(s2, off);
    }
    const int wave = tid >> 6;
    if ((tid & 63) == 0) { s_red[wave] = s; s_red[4 + wave] = s2; }
    __syncthreads();
    const float ts   = s_red[0] + s_red[1] + s_red[2] + s_red[3];
    const float ts2  = s_red[4] + s_red[5] + s_red[6] + s_red[7];
    const float mean = ts * (1.0f / HID);
    const float var  = ts2 * (1.0f / HID) - mean * mean;
    const float rstd = rsqrtf(var + EPS_LN);

#pragma unroll
    for (int j = 0; j < 8; ++j) {
        const int h = tid * 8 + j;
        out[(size_t)token * HID + h] = (acc[j] - mean) * rstd * gamma[h] + beta[h];
    }
}

extern "C" void kernel_launch(void* const* d_in, const int* in_sizes, int n_in,
                              void* d_out, int out_size, void* d_ws, size_t ws_size,
                              hipStream_t stream) {
    const int*   ids    = (const int*)d_in[0];
    const float* proj_w = (const float*)d_in[1];
    const float* gamma  = (const float*)d_in[2];
    const float* beta   = (const float*)d_in[3];
    float*       out    = (float*)d_out;

    const size_t wt_bytes   = (size_t)TROWS * HID * sizeof(__hip_bfloat16);  // ~8.4 MB
    const size_t part_bytes = (size_t)NTOK * NSLICE * sizeof(float2);        // 512 KB
    const size_t uid_bytes  = (size_t)NTOK * UIDS * sizeof(int);             // 3 MB
    const size_t cnt_bytes  = (size_t)NTOK * sizeof(int);                    // 64 KB
    const size_t xbf_bytes  = (size_t)NTOK * HID * sizeof(__hip_bfloat16);   // 67 MB

    const size_t off_part = wt_bytes;
    const size_t off_uid  = off_part + part_bytes;
    const size_t off_cnt  = off_uid + uid_bytes;
    const size_t off_xh_A = off_cnt + cnt_bytes;                 // full layout
    const size_t off_xh_B = off_part + part_bytes;               // no-dedupe layout

    const size_t need_A = off_xh_A + xbf_bytes;   // ~79 MB
    const size_t need_B = off_xh_B + xbf_bytes;   // ~76 MB
    const size_t need_C = wt_bytes + part_bytes;  // ~9 MB

    if (ws_size >= need_C) {
        __hip_bfloat16* Wt = (__hip_bfloat16*)d_ws;
        float2* partials   = (float2*)((char*)d_ws + off_part);

        dim3 tb(32, 8), tg(SDRN / 32, HID / 32);
        transpose_cvt<<<tg, tb, 0, stream>>>(proj_w, Wt);
        zero_pad_row<<<1, 256, 0, stream>>>(Wt);

        if (ws_size >= need_A) {
            int* uidp           = (int*)((char*)d_ws + off_uid);
            int* ucnt           = (int*)((char*)d_ws + off_cnt);
            __hip_bfloat16* xbf = (__hip_bfloat16*)((char*)d_ws + off_xh_A);
            dedup_k<<<NTOK / 4, 256, 0, stream>>>(ids, uidp, ucnt);
            sdr_gather_p1_two<<<NTOK / 2, 256, 0, stream>>>(uidp, ucnt, Wt, xbf, partials);
            sdr_ln_p2_bf<<<NTOK, 256, 0, stream>>>(xbf, partials, gamma, beta, out);
        } else if (ws_size >= need_B) {
            __hip_bfloat16* xbf = (__hip_bfloat16*)((char*)d_ws + off_xh_B);
            sdr_gather_p1<true><<<NTOK, 256, 0, stream>>>(ids, Wt, xbf, partials);
            sdr_ln_p2_bf<<<NTOK, 256, 0, stream>>>(xbf, partials, gamma, beta, out);
        } else {
            sdr_gather_p1<false><<<NTOK, 256, 0, stream>>>(ids, Wt, out, partials);
            sdr_ln_p2_inplace<<<NTOK, 256, 0, stream>>>(out, partials, gamma, beta);
        }
    } else {
        sdr_gather_ln_notr<<<NTOK, 256, 0, stream>>>(ids, proj_w, gamma, beta, out);
    }
}

// Round 14
// 166.897 us; speedup vs baseline: 1.0088x; 1.0088x over previous
//
#include <hip/hip_runtime.h>
#include <hip/hip_bf16.h>

// Problem constants (match reference)
#define BB      4
#define SS      4096
#define WW      41
#define SDRN    2048
#define HID     2048
#define NTOK    (BB * SS)
#define EPS_LN  1e-5f
#define NSLICE  4
#define SLICE_H 512        // HID / NSLICE
#define PADID   SDRN       // index of the all-zeros padding row
#define TROWS   (SDRN + 1) // table rows incl. zero row
#define UIDS    48         // padded id-list stride (ints)
#define NKFIX   44         // fixed row count (dedup pads to 44 with PADID)

typedef float        f32x4 __attribute__((ext_vector_type(4)));
typedef float        f32x2 __attribute__((ext_vector_type(2)));
typedef unsigned int u32x4 __attribute__((ext_vector_type(4)));

static __device__ __forceinline__ unsigned short bf16bits(float f) {
    return __builtin_bit_cast(unsigned short, __float2bfloat16(f));
}

// ---------------------------------------------------------------------------
// Kernel 1a: transpose+convert proj_w [HID][SDRN] f32 -> Wt [TROWS][HID] bf16
// ---------------------------------------------------------------------------
__global__ __launch_bounds__(256) void transpose_cvt(const float* __restrict__ in,
                                                     __hip_bfloat16* __restrict__ out) {
    __shared__ float tile[32][33];
    int x = blockIdx.x * 32 + threadIdx.x;  // n
    int y = blockIdx.y * 32 + threadIdx.y;  // h
#pragma unroll
    for (int j = 0; j < 32; j += 8)
        tile[threadIdx.y + j][threadIdx.x] = in[(size_t)(y + j) * SDRN + x];
    __syncthreads();
    x = blockIdx.y * 32 + threadIdx.x;      // h
    y = blockIdx.x * 32 + threadIdx.y;      // n
#pragma unroll
    for (int j = 0; j < 32; j += 8)
        out[(size_t)(y + j) * HID + x] = __float2bfloat16(tile[threadIdx.x][threadIdx.y + j]);
}

// Kernel 1b: zero the padding row (row PADID = 4096 B)
__global__ void zero_pad_row(__hip_bfloat16* __restrict__ Wt) {
    u32x4 z = {0u, 0u, 0u, 0u};
    *((u32x4*)(Wt + (size_t)PADID * HID) + threadIdx.x) = z;  // 256 x 16 B
}

// ---------------------------------------------------------------------------
// Kernel 1c: per-token dedupe (hoisted, R12-proven). One wave per token.
// Writes a FULL 44-entry id list (unique ids then PADID padding) + count.
// ---------------------------------------------------------------------------
__global__ __launch_bounds__(256) void dedup_k(const int* __restrict__ ids,
                                               int* __restrict__ uidp,
                                               int* __restrict__ ucnt) {
    const int wave  = threadIdx.x >> 6;
    const int lane  = threadIdx.x & 63;
    const int token = blockIdx.x * 4 + wave;

    int myid = (lane < WW) ? ids[(size_t)token * WW + lane] : 0;
    int keep = (lane < WW) ? 1 : 0;
#pragma unroll
    for (int j = 0; j < WW; ++j) {
        const int idj = __shfl(myid, j);
        if (j < lane && lane < WW && idj == myid) keep = 0;
    }
    const unsigned long long km = __ballot(keep);
    const int nkeep = __popcll(km);
    const int nk4   = (nkeep + 3) & ~3;             // <= 44
    int* dst = uidp + (size_t)token * UIDS;
    if (keep) {
        const int rank = __popcll(km & ((1ull << lane) - 1ull));
        dst[rank] = myid;
    }
    if (lane >= nkeep && lane < NKFIX) dst[lane] = PADID;
    if (lane == 0) ucnt[token] = nk4;
}

#define ACC8(u, a0, a1, a2, a3)                                                 \
    { f32x2 t;                                                                  \
      t.x = __uint_as_float((u).x << 16); t.y = __uint_as_float((u).x & 0xffff0000u); a0 += t; \
      t.x = __uint_as_float((u).y << 16); t.y = __uint_as_float((u).y & 0xffff0000u); a1 += t; \
      t.x = __uint_as_float((u).z << 16); t.y = __uint_as_float((u).z & 0xffff0000u); a2 += t; \
      t.x = __uint_as_float((u).w << 16); t.y = __uint_as_float((u).w & 0xffff0000u); a3 += t; }

// ---------------------------------------------------------------------------
// Pass 1 (R12 structure, fixed-trip fully-unrolled loop): one 512-wide h-slice
// per wave's token; slice pinned via blockIdx&7 (L2-resident table slice).
// All 44 rows processed unconditionally (padding rows are zeros, exact).
// Fully unrolled -> readlane with immediate lane index, loads scheduled early.
// ---------------------------------------------------------------------------
__global__ __launch_bounds__(256) void sdr_gather_p1_fix(
    const int* __restrict__ uidp, const __hip_bfloat16* __restrict__ Wt,
    __hip_bfloat16* __restrict__ xbf, float2* __restrict__ partials) {
    const int b     = blockIdx.x;
    const int sub   = b & 1;
    const int slice = (b & 7) >> 1;                 // 4 slices x 2 XCDs
    const int tg    = ((b >> 3) << 1) | sub;        // token group (4 tokens)
    const int wave  = threadIdx.x >> 6;
    const int lane  = threadIdx.x & 63;
    const int token = tg * 4 + wave;

    const int cid = uidp[(size_t)token * UIDS + (lane < NKFIX ? lane : 0)];

    f32x2 a0 = {0.f, 0.f}, a1 = {0.f, 0.f}, a2 = {0.f, 0.f}, a3 = {0.f, 0.f};
    const int lofs = slice * SLICE_H + lane * 8;    // element offset in a row
    const unsigned int* W32 = (const unsigned int*)Wt;
    const int lo2 = lofs >> 1;

#pragma unroll
    for (int i = 0; i < NKFIX; i += 4) {
        const int id0 = __builtin_amdgcn_readlane(cid, i);
        const int id1 = __builtin_amdgcn_readlane(cid, i + 1);
        const int id2 = __builtin_amdgcn_readlane(cid, i + 2);
        const int id3 = __builtin_amdgcn_readlane(cid, i + 3);
        const u32x4 u0 = *(const u32x4*)(W32 + (size_t)id0 * (HID / 2) + lo2);
        const u32x4 u1 = *(const u32x4*)(W32 + (size_t)id1 * (HID / 2) + lo2);
        const u32x4 u2 = *(const u32x4*)(W32 + (size_t)id2 * (HID / 2) + lo2);
        const u32x4 u3 = *(const u32x4*)(W32 + (size_t)id3 * (HID / 2) + lo2);
        ACC8(u0, a0, a1, a2, a3);
        ACC8(u1, a0, a1, a2, a3);
        ACC8(u2, a0, a1, a2, a3);
        ACC8(u3, a0, a1, a2, a3);
    }

    // per-wave partial (sum, sumsq) for this slice
    float s  = a0.x + a0.y + a1.x + a1.y + a2.x + a2.y + a3.x + a3.y;
    float s2 = a0.x * a0.x + a0.y * a0.y + a1.x * a1.x + a1.y * a1.y +
               a2.x * a2.x + a2.y * a2.y + a3.x * a3.x + a3.y * a3.y;
#pragma unroll
    for (int off = 1; off < 64; off <<= 1) {
        s  += __shfl_xor(s, off);
        s2 += __shfl_xor(s2, off);
    }
    if (lane == 0) {
        float2 p; p.x = s; p.y = s2;
        partials[(size_t)token * NSLICE + slice] = p;
    }

    // write pre-LN x (bf16, nontemporal)
    u32x4 o;
    o.x = (unsigned)bf16bits(a0.x) | ((unsigned)bf16bits(a0.y) << 16);
    o.y = (unsigned)bf16bits(a1.x) | ((unsigned)bf16bits(a1.y) << 16);
    o.z = (unsigned)bf16bits(a2.x) | ((unsigned)bf16bits(a2.y) << 16);
    o.w = (unsigned)bf16bits(a3.x) | ((unsigned)bf16bits(a3.y) << 16);
    __builtin_nontemporal_store(o, (u32x4*)(xbf + (size_t)token * HID + lofs));
}

// ---------------------------------------------------------------------------
// Pass 1 fallback (R10-proven single-token, inline dedupe), XBF variants.
// ---------------------------------------------------------------------------
template <bool XBF>
__global__ __launch_bounds__(256) void sdr_gather_p1(
    const int* __restrict__ ids, const __hip_bfloat16* __restrict__ Wt,
    void* __restrict__ xout, float2* __restrict__ partials) {
    const int b     = blockIdx.x;
    const int sub   = b & 1;
    const int slice = (b & 7) >> 1;
    const int tg    = ((b >> 3) << 1) | sub;
    const int wave  = threadIdx.x >> 6;
    const int lane  = threadIdx.x & 63;
    const int token = tg * 4 + wave;

    __shared__ int s_uids[4][44];

    int myid = (lane < WW) ? ids[(size_t)token * WW + lane] : 0;
    int keep = (lane < WW) ? 1 : 0;
#pragma unroll
    for (int j = 0; j < WW; ++j) {
        const int idj = __shfl(myid, j);
        if (j < lane && lane < WW && idj == myid) keep = 0;
    }
    const unsigned long long km = __ballot(keep);
    const int nkeep = __popcll(km);
    const int nk4   = (nkeep + 3) & ~3;
    if (keep) {
        const int rank = __popcll(km & ((1ull << lane) - 1ull));
        s_uids[wave][rank] = myid;
    }
    if (lane >= nkeep && lane < nk4) s_uids[wave][lane] = PADID;
    const int cid = s_uids[wave][lane < 44 ? lane : 0];

    f32x2 a0 = {0.f, 0.f}, a1 = {0.f, 0.f}, a2 = {0.f, 0.f}, a3 = {0.f, 0.f};
    const int lofs = slice * SLICE_H + lane * 8;

    for (int i = 0; i < nk4; i += 4) {
        const int id0 = __builtin_amdgcn_readlane(cid, i);
        const int id1 = __builtin_amdgcn_readlane(cid, i + 1);
        const int id2 = __builtin_amdgcn_readlane(cid, i + 2);
        const int id3 = __builtin_amdgcn_readlane(cid, i + 3);
        const u32x4 u0 = *(const u32x4*)((const unsigned int*)Wt + (size_t)id0 * (HID / 2) + (lofs >> 1));
        const u32x4 u1 = *(const u32x4*)((const unsigned int*)Wt + (size_t)id1 * (HID / 2) + (lofs >> 1));
        const u32x4 u2 = *(const u32x4*)((const unsigned int*)Wt + (size_t)id2 * (HID / 2) + (lofs >> 1));
        const u32x4 u3 = *(const u32x4*)((const unsigned int*)Wt + (size_t)id3 * (HID / 2) + (lofs >> 1));
        ACC8(u0, a0, a1, a2, a3);
        ACC8(u1, a0, a1, a2, a3);
        ACC8(u2, a0, a1, a2, a3);
        ACC8(u3, a0, a1, a2, a3);
    }

    float s  = a0.x + a0.y + a1.x + a1.y + a2.x + a2.y + a3.x + a3.y;
    float s2 = a0.x * a0.x + a0.y * a0.y + a1.x * a1.x + a1.y * a1.y +
               a2.x * a2.x + a2.y * a2.y + a3.x * a3.x + a3.y * a3.y;
#pragma unroll
    for (int off = 1; off < 64; off <<= 1) {
        s  += __shfl_xor(s, off);
        s2 += __shfl_xor(s2, off);
    }
    if (lane == 0) {
        float2 p; p.x = s; p.y = s2;
        partials[(size_t)token * NSLICE + slice] = p;
    }

    if (XBF) {
        u32x4 o;
        o.x = (unsigned)bf16bits(a0.x) | ((unsigned)bf16bits(a0.y) << 16);
        o.y = (unsigned)bf16bits(a1.x) | ((unsigned)bf16bits(a1.y) << 16);
        o.z = (unsigned)bf16bits(a2.x) | ((unsigned)bf16bits(a2.y) << 16);
        o.w = (unsigned)bf16bits(a3.x) | ((unsigned)bf16bits(a3.y) << 16);
        __hip_bfloat16* xb = (__hip_bfloat16*)xout;
        __builtin_nontemporal_store(o, (u32x4*)(xb + (size_t)token * HID + lofs));
    } else {
        float* xf = (float*)xout;
        f32x4 v0; v0.x = a0.x; v0.y = a0.y; v0.z = a1.x; v0.w = a1.y;
        f32x4 v1; v1.x = a2.x; v1.y = a2.y; v1.z = a3.x; v1.w = a3.y;
        f32x4* xr = (f32x4*)(xf + (size_t)token * HID + lofs);
        __builtin_nontemporal_store(v0, xr);
        __builtin_nontemporal_store(v1, xr + 1);
    }
}

// ---------------------------------------------------------------------------
// Pass 2a: x is bf16 in ws -> normalize -> f32 out
// ---------------------------------------------------------------------------
__global__ __launch_bounds__(256) void sdr_ln_p2_bf(
    const __hip_bfloat16* __restrict__ xbf, const float2* __restrict__ partials,
    const float* __restrict__ gamma, const float* __restrict__ beta,
    float* __restrict__ out) {
    const int token = blockIdx.x;
    const int tid   = threadIdx.x;

    float s = 0.f, s2 = 0.f;
#pragma unroll
    for (int j = 0; j < NSLICE; ++j) {
        const float2 p = partials[(size_t)token * NSLICE + j];
        s += p.x; s2 += p.y;
    }
    const float mean = s * (1.0f / HID);
    const float var  = s2 * (1.0f / HID) - mean * mean;
    const float rstd = rsqrtf(var + EPS_LN);

    const u32x4 u = *((const u32x4*)(xbf + (size_t)token * HID) + tid);
    float xv[8];
    xv[0] = __uint_as_float(u.x << 16); xv[1] = __uint_as_float(u.x & 0xffff0000u);
    xv[2] = __uint_as_float(u.y << 16); xv[3] = __uint_as_float(u.y & 0xffff0000u);
    xv[4] = __uint_as_float(u.z << 16); xv[5] = __uint_as_float(u.z & 0xffff0000u);
    xv[6] = __uint_as_float(u.w << 16); xv[7] = __uint_as_float(u.w & 0xffff0000u);

    const f32x4* g4 = (const f32x4*)gamma + tid * 2;
    const f32x4* b4 = (const f32x4*)beta  + tid * 2;
    const f32x4 g0 = g4[0], g1 = g4[1];
    const f32x4 be0 = b4[0], be1 = b4[1];
    f32x4 r0, r1;
    r0.x = (xv[0] - mean) * rstd * g0.x + be0.x;
    r0.y = (xv[1] - mean) * rstd * g0.y + be0.y;
    r0.z = (xv[2] - mean) * rstd * g0.z + be0.z;
    r0.w = (xv[3] - mean) * rstd * g0.w + be0.w;
    r1.x = (xv[4] - mean) * rstd * g1.x + be1.x;
    r1.y = (xv[5] - mean) * rstd * g1.y + be1.y;
    r1.z = (xv[6] - mean) * rstd * g1.z + be1.z;
    r1.w = (xv[7] - mean) * rstd * g1.w + be1.w;
    f32x4* o4 = (f32x4*)(out + (size_t)token * HID) + tid * 2;
    __builtin_nontemporal_store(r0, o4);
    __builtin_nontemporal_store(r1, o4 + 1);
}

// ---------------------------------------------------------------------------
// Pass 2b: x is f32 in d_out -> normalize in place
// ---------------------------------------------------------------------------
__global__ __launch_bounds__(256) void sdr_ln_p2_inplace(
    float* __restrict__ x, const float2* __restrict__ partials,
    const float* __restrict__ gamma, const float* __restrict__ beta) {
    const int token = blockIdx.x;
    const int tid   = threadIdx.x;

    float s = 0.f, s2 = 0.f;
#pragma unroll
    for (int j = 0; j < NSLICE; ++j) {
        const float2 p = partials[(size_t)token * NSLICE + j];
        s += p.x; s2 += p.y;
    }
    const float mean = s * (1.0f / HID);
    const float var  = s2 * (1.0f / HID) - mean * mean;
    const float rstd = rsqrtf(var + EPS_LN);

    float4*       xr = (float4*)(x + (size_t)token * HID) + tid * 2;
    const float4* g4 = (const float4*)gamma + tid * 2;
    const float4* b4 = (const float4*)beta  + tid * 2;
    float4 a = xr[0], bq = xr[1];
    const float4 g0 = g4[0], g1 = g4[1];
    const float4 be0 = b4[0], be1 = b4[1];
    a.x  = (a.x  - mean) * rstd * g0.x + be0.x;
    a.y  = (a.y  - mean) * rstd * g0.y + be0.y;
    a.z  = (a.z  - mean) * rstd * g0.z + be0.z;
    a.w  = (a.w  - mean) * rstd * g0.w + be0.w;
    bq.x = (bq.x - mean) * rstd * g1.x + be1.x;
    bq.y = (bq.y - mean) * rstd * g1.y + be1.y;
    bq.z = (bq.z - mean) * rstd * g1.z + be1.z;
    bq.w = (bq.w - mean) * rstd * g1.w + be1.w;
    xr[0] = a;
    xr[1] = bq;
}

// ---------------------------------------------------------------------------
// Fallback (tiny ws): gather directly from proj_w columns, fused LN.
// ---------------------------------------------------------------------------
__global__ __launch_bounds__(256) void sdr_gather_ln_notr(
    const int* __restrict__ ids, const float* __restrict__ W,
    const float* __restrict__ gamma, const float* __restrict__ beta,
    float* __restrict__ out) {
    const int token = blockIdx.x;
    const int tid   = threadIdx.x;

    __shared__ int   s_ids[WW];
    __shared__ int   s_keep[WW];
    __shared__ float s_red[8];

    if (tid < WW) s_ids[tid] = ids[(size_t)token * WW + tid];
    __syncthreads();
    if (tid < WW) {
        const int v = s_ids[tid];
        int keep = 1;
        for (int j = 0; j < tid; ++j)
            if (s_ids[j] == v) { keep = 0; break; }
        s_keep[tid] = keep;
    }
    __syncthreads();

    float acc[8] = {0.f};
    for (int i = 0; i < WW; ++i) {
        if (!s_keep[i]) continue;
        const int id = s_ids[i];
#pragma unroll
        for (int j = 0; j < 8; ++j) {
            const int h = tid * 8 + j;
            acc[j] += W[(size_t)h * SDRN + id];
        }
    }
    float s = 0.f, s2 = 0.f;
#pragma unroll
    for (int j = 0; j < 8; ++j) { s += acc[j]; s2 += acc[j] * acc[j]; }
#pragma unroll
    for (int off = 1; off < 64; off <<= 1) {
        s  += __shfl_xor(s, off);
        s2 += __shfl_xor(s2, off);
    }
    const int wave = tid >> 6;
    if ((tid & 63) == 0) { s_red[wave] = s; s_red[4 + wave] = s2; }
    __syncthreads();
    const float ts   = s_red[0] + s_red[1] + s_red[2] + s_red[3];
    const float ts2  = s_red[4] + s_red[5] + s_red[6] + s_red[7];
    const float mean = ts * (1.0f / HID);
    const float var  = ts2 * (1.0f / HID) - mean * mean;
    const float rstd = rsqrtf(var + EPS_LN);

#pragma unroll
    for (int j = 0; j < 8; ++j) {
        const int h = tid * 8 + j;
        out[(size_t)token * HID + h] = (acc[j] - mean) * rstd * gamma[h] + beta[h];
    }
}

extern "C" void kernel_launch(void* const* d_in, const int* in_sizes, int n_in,
                              void* d_out, int out_size, void* d_ws, size_t ws_size,
                              hipStream_t stream) {
    const int*   ids    = (const int*)d_in[0];
    const float* proj_w = (const float*)d_in[1];
    const float* gamma  = (const float*)d_in[2];
    const float* beta   = (const float*)d_in[3];
    float*       out    = (float*)d_out;

    const size_t wt_bytes   = (size_t)TROWS * HID * sizeof(__hip_bfloat16);  // ~8.4 MB
    const size_t part_bytes = (size_t)NTOK * NSLICE * sizeof(float2);        // 512 KB
    const size_t uid_bytes  = (size_t)NTOK * UIDS * sizeof(int);             // 3 MB
    const size_t cnt_bytes  = (size_t)NTOK * sizeof(int);                    // 64 KB
    const size_t xbf_bytes  = (size_t)NTOK * HID * sizeof(__hip_bfloat16);   // 67 MB

    const size_t off_part = wt_bytes;
    const size_t off_uid  = off_part + part_bytes;
    const size_t off_cnt  = off_uid + uid_bytes;
    const size_t off_xh_A = off_cnt + cnt_bytes;                 // full layout
    const size_t off_xh_B = off_part + part_bytes;               // no-dedupe layout

    const size_t need_A = off_xh_A + xbf_bytes;   // ~79 MB
    const size_t need_B = off_xh_B + xbf_bytes;   // ~76 MB
    const size_t need_C = wt_bytes + part_bytes;  // ~9 MB

    if (ws_size >= need_C) {
        __hip_bfloat16* Wt = (__hip_bfloat16*)d_ws;
        float2* partials   = (float2*)((char*)d_ws + off_part);

        dim3 tb(32, 8), tg(SDRN / 32, HID / 32);
        transpose_cvt<<<tg, tb, 0, stream>>>(proj_w, Wt);
        zero_pad_row<<<1, 256, 0, stream>>>(Wt);

        if (ws_size >= need_A) {
            int* uidp           = (int*)((char*)d_ws + off_uid);
            int* ucnt           = (int*)((char*)d_ws + off_cnt);
            __hip_bfloat16* xbf = (__hip_bfloat16*)((char*)d_ws + off_xh_A);
            dedup_k<<<NTOK / 4, 256, 0, stream>>>(ids, uidp, ucnt);
            sdr_gather_p1_fix<<<NTOK, 256, 0, stream>>>(uidp, Wt, xbf, partials);
            sdr_ln_p2_bf<<<NTOK, 256, 0, stream>>>(xbf, partials, gamma, beta, out);
        } else if (ws_size >= need_B) {
            __hip_bfloat16* xbf = (__hip_bfloat16*)((char*)d_ws + off_xh_B);
            sdr_gather_p1<true><<<NTOK, 256, 0, stream>>>(ids, Wt, xbf, partials);
            sdr_ln_p2_bf<<<NTOK, 256, 0, stream>>>(xbf, partials, gamma, beta, out);
        } else {
            sdr_gather_p1<false><<<NTOK, 256, 0, stream>>>(ids, Wt, out, partials);
            sdr_ln_p2_inplace<<<NTOK, 256, 0, stream>>>(out, partials, gamma, beta);
        }
    } else {
        sdr_gather_ln_notr<<<NTOK, 256, 0, stream>>>(ids, proj_w, gamma, beta, out);
    }
}